// Round 10
// baseline (548.633 us; speedup 1.0000x reference)
//
#include <hip/hip_runtime.h>

// StructuredElmanCell via MFMA, split-precision (hi/lo) bf16 inputs.
// Wave owns a 16n x 16p H-tile in fp32 regs; K=32 MFMA carries
// (Bhi*Xhi)+(Bhi*Xlo)+(Blo*Xhi)+(Blo*Xlo) across its 4 k-octets.
// R10: TIME-SPLIT to 2 waves/SIMD. alpha<0.5 and |silu'|<=1.0998 make the
// recurrence contractive (factor <=0.55/step), so half1 starts at t=496 with
// H=0, warms up 48 steps (error 0.55^48 ~ 3e-13), and emits t in [544,1024);
// half0 emits t in [0,544). The co-resident second wave supplies the TLP that
// single-wave ILP couldn't: R8/R9 were stuck at ~50% VALUBusy, 1 wave/SIMD.

namespace {
constexpr int T  = 1024;
constexpr int BS = 4;
constexpr int NH = 16;
constexpr int DS = 32;
constexpr int HD = 128;
constexpr int R  = 8;
constexpr int DI = NH * HD;              // 2048
constexpr int GROUP = 8;

// byte strides
constexpr unsigned B_T  = BS * NH * DS * R * 4;  // 65536 B per t
constexpr unsigned X_T  = BS * NH * HD * R * 4;  // 262144 B per t
constexpr unsigned B_G  = B_T * GROUP;
constexpr unsigned X_G  = X_T * GROUP;
constexpr unsigned A_T4 = BS * NH * 4;           // 256 B per t
constexpr unsigned A_G  = A_T4 * GROUP;          // 2048 B per group
constexpr unsigned ZO_T = BS * DI * 4;           // 32768 B per t (z and out)
constexpr unsigned ZO_G = ZO_T * GROUP;          // 262144 B per group

constexpr int SPLIT_T  = 544;   // half0 emits t<544 (68 groups, no warmup)
constexpr int WARM     = 48;    // half1 warmup steps = 6 groups
constexpr int T_BEGIN1 = SPLIT_T - WARM;         // 496
constexpr int NG0      = SPLIT_T / GROUP;        // 68
constexpr int NG1      = (T - T_BEGIN1) / GROUP; // 66

constexpr float LOG2E = 1.4426950408889634f;

typedef __attribute__((ext_vector_type(8))) short bf16x8;
typedef __attribute__((ext_vector_type(4))) float f32x4;
typedef __attribute__((ext_vector_type(4))) unsigned u32x4;

__device__ __forceinline__ float fast_exp(float x) {
    return __builtin_amdgcn_exp2f(x * LOG2E);
}
__device__ __forceinline__ float fast_silu(float x) {
    return x * __builtin_amdgcn_rcpf(1.0f + __builtin_amdgcn_exp2f(x * -LOG2E));
}
__device__ __forceinline__ float4 ld4(const void* p, unsigned off) {
    return *(const float4*)((const char*)p + off);
}
__device__ __forceinline__ float ld1(const void* p, unsigned off) {
    return *(const float*)((const char*)p + off);
}

// bf16-pair pack: low16 = sel(a), high16 = sel(b); hi = top-16 truncation,
// lo = exact fp32 remainder truncated to bf16.
__device__ __forceinline__ unsigned pack_pair(float a, float b, bool useHi) {
    unsigned ua = __float_as_uint(a), ub = __float_as_uint(b);
    unsigned hi = __builtin_amdgcn_perm(ub, ua, 0x07060302u);
    float la = a - __uint_as_float(ua & 0xffff0000u);   // exact
    float lb = b - __uint_as_float(ub & 0xffff0000u);
    unsigned lo = __builtin_amdgcn_perm(__float_as_uint(lb),
                                        __float_as_uint(la), 0x07060302u);
    return useHi ? hi : lo;
}
__device__ __forceinline__ u32x4 pack_frag(const float4& v0, const float4& v1,
                                           bool useHi) {
    u32x4 u;
    u.x = pack_pair(v0.x, v0.y, useHi);
    u.y = pack_pair(v0.z, v0.w, useHi);
    u.z = pack_pair(v1.x, v1.y, useHi);
    u.w = pack_pair(v1.z, v1.w, useHi);
    return u;
}

// ---------------- pass 0: alpha = 1/(2+exp(ar+ab)) == sigmoid(-softplus) ---
__global__ __launch_bounds__(256)
void alpha_kernel(const float* __restrict__ ar_, const float* __restrict__ ab_,
                  float* __restrict__ alpha_) {
    int i = blockIdx.x * 256 + threadIdx.x;          // [T,BS,NH] flat
    float v = ar_[i] + ab_[i & (NH - 1)];
    alpha_[i] = __builtin_amdgcn_rcpf(2.0f + fast_exp(v));
}

// ---------------- pass 1: MFMA scan, time-split ----------------------------
template<bool PRE>
__global__ __launch_bounds__(256, 2)
void elman_mfma_kernel(const float* __restrict__ B_,
                       const float* __restrict__ X_,
                       const float* __restrict__ a_,   // PRE? alpha : alpha_raw
                       const float* __restrict__ ab_,
                       const float* __restrict__ z_,
                       const float* __restrict__ H0_,
                       float* __restrict__ out_,
                       float* __restrict__ Hf_)
{
    __shared__ float ybuf[2][2][GROUP][9][16];  // [parity][pcl][stage][src+pad][p]

    const int half = blockIdx.x >> 8;           // 0: t<544, 1: t>=496
    const int blk  = blockIdx.x & 255;
    const int lane = threadIdx.x & 63;
    const int W    = blk * 4 + (threadIdx.x >> 6); // tile 0..1023
    const int nc   = W & 1;
    const int pc   = (W >> 1) & 7;
    const int bh   = W >> 4;
    const int h    = bh & (NH - 1);
    const int b    = bh >> 4;
    const int n0   = nc * 16;
    const int p0   = pc * 16;
    const int pcl  = pc & 1;
    const int l15  = lane & 15;
    const int sl   = lane >> 4;          // 0..3
    const int st   = nc * 4 + sl;        // this lane's gate stage AND src id

    const int t_begin   = half ? T_BEGIN1 : 0;
    const int ngroups   = half ? NG1 : NG0;
    const int emit_from = half ? (WARM / GROUP) : 0;

    const bool useBhi = (lane < 32);
    const bool useXhi = ((lane & 16) == 0);

    const unsigned hoff = (unsigned)bh * 4096u
                        + (unsigned)(n0 + sl * 4) * 128u
                        + (unsigned)(p0 + l15);
    f32x4 H;
    if (half) {
        H.x = 0.f; H.y = 0.f; H.z = 0.f; H.w = 0.f;   // warmup: contraction
    } else {
        H.x = H0_[hoff];       H.y = H0_[hoff + 128];
        H.z = H0_[hoff + 256]; H.w = H0_[hoff + 384];
    }

    const float abv = PRE ? 0.0f : ab_[h];

    // byte offsets off SGPR bases, shifted to t_begin
    unsigned bB = ((unsigned)bh * (DS * R) + (unsigned)(n0 + l15) * R) * 4u
                + (unsigned)t_begin * B_T;
    unsigned bX = ((unsigned)bh * (HD * R) + (unsigned)(p0 + l15) * R) * 4u
                + (unsigned)t_begin * X_T;
    unsigned bA = ((unsigned)(lane & 7) * 64u + (unsigned)bh) * 4u
                + (unsigned)t_begin * A_T4;
    const unsigned zo0 = ((unsigned)st * 8192u + (unsigned)b * 2048u
                        + (unsigned)h * 128u + (unsigned)(p0 + l15)) * 4u
                        + (unsigned)t_begin * ZO_T;
    unsigned bZ = zo0, bO = zo0;

    float4 rB0[GROUP], rB1[GROUP], rX0[GROUP], rX1[GROUP];
    u32x4 A0[GROUP], B0f[GROUP], A1[GROUP], B1f[GROUP];
    float py[GROUP];
    float avA, avB, zvA, zvB;

    // ---- prologue: raw g0 -> pack into set0; raw g1 into ring -------------
    #pragma unroll
    for (int s = 0; s < GROUP; ++s) {
        rB0[s] = ld4(B_, bB + (unsigned)s * B_T);
        rB1[s] = ld4(B_, bB + (unsigned)s * B_T + 16u);
        rX0[s] = ld4(X_, bX + (unsigned)s * X_T);
        rX1[s] = ld4(X_, bX + (unsigned)s * X_T + 16u);
    }
    bB += B_G; bX += X_G;
    avA = ld1(a_, bA); bA += A_G;
    zvA = ld1(z_, bZ); bZ += ZO_G;
    #pragma unroll
    for (int s = 0; s < GROUP; ++s) {
        A0[s]  = pack_frag(rB0[s], rB1[s], useBhi);
        B0f[s] = pack_frag(rX0[s], rX1[s], useXhi);
    }
    #pragma unroll
    for (int s = 0; s < GROUP; ++s) {
        rB0[s] = ld4(B_, bB + (unsigned)s * B_T);
        rB1[s] = ld4(B_, bB + (unsigned)s * B_T + 16u);
        rX0[s] = ld4(X_, bX + (unsigned)s * X_T);
        rX1[s] = ld4(X_, bX + (unsigned)s * X_T + 16u);
    }
    bB += B_G; bX += X_G;   // now points at g2

    auto step = [&](const u32x4& af, const u32x4& bf, float avC, int s) {
        float ar = __int_as_float(
            __builtin_amdgcn_readlane(__float_as_int(avC), s));
        float alpha = PRE ? ar
                          : __builtin_amdgcn_rcpf(2.0f + fast_exp(ar + abv));
        f32x4 c;
        c.x = alpha * H.x; c.y = alpha * H.y;
        c.z = alpha * H.z; c.w = alpha * H.w;
        f32x4 d = __builtin_amdgcn_mfma_f32_16x16x32_bf16(
            __builtin_bit_cast(bf16x8, af), __builtin_bit_cast(bf16x8, bf),
            c, 0, 0, 0);
        H.x = fast_silu(d.x); H.y = fast_silu(d.y);
        H.z = fast_silu(d.z); H.w = fast_silu(d.w);
        py[s] = (H.x + H.y) + (H.z + H.w);
    };

    auto exchange = [&](int par, float zvC, bool emit) {
        #pragma unroll
        for (int s = 0; s < GROUP; ++s)
            ybuf[par][pcl][s][st][l15] = py[s];
        asm volatile("s_waitcnt lgkmcnt(0)" ::: "memory");
        __builtin_amdgcn_s_barrier();
        __builtin_amdgcn_sched_barrier(0);
        asm volatile("" ::: "memory");
        float y2 = 0.0f;
        #pragma unroll
        for (int k = 0; k < 8; ++k)
            y2 += ybuf[par][pcl][st][k][l15];
        float g = y2 * fast_silu(zvC + y2);
        if (emit) *(float*)((char*)out_ + bO) = g;
        bO += ZO_G;
    };

    // body for one group: steps from (Ac,Bc); pack ring -> (An,Bn); refill ring
    auto body = [&](u32x4 (&Ac)[GROUP], u32x4 (&Bc)[GROUP],
                    u32x4 (&An)[GROUP], u32x4 (&Bn)[GROUP],
                    float avC, float& avN, float zvC, float& zvN,
                    int par, bool refill, bool emit) {
        avN = ld1(a_, bA); bA += A_G;
        zvN = ld1(z_, bZ); bZ += ZO_G;
        #pragma unroll
        for (int s = 0; s < GROUP; ++s) {
            step(Ac[s], Bc[s], avC, s);
            An[s] = pack_frag(rB0[s], rB1[s], useBhi);
            Bn[s] = pack_frag(rX0[s], rX1[s], useXhi);
            if (refill) {
                rB0[s] = ld4(B_, bB + (unsigned)s * B_T);
                rB1[s] = ld4(B_, bB + (unsigned)s * B_T + 16u);
                rX0[s] = ld4(X_, bX + (unsigned)s * X_T);
                rX1[s] = ld4(X_, bX + (unsigned)s * X_T + 16u);
            }
        }
        if (refill) { bB += B_G; bX += X_G; }
        exchange(par, zvC, emit);
    };

    // main: ping-pong pairs; refill g+2 valid through g = ngroups-3
    int g = 0;
    #pragma unroll 1
    for (int gg = 0; gg < (ngroups - 2) / 2; ++gg) {
        body(A0, B0f, A1, B1f, avA, avB, zvA, zvB, 0, true, g >= emit_from); ++g;
        body(A1, B1f, A0, B0f, avB, avA, zvB, zvA, 1, true, g >= emit_from); ++g;
    }
    // group ngroups-2: pack last group from ring, no refill
    body(A0, B0f, A1, B1f, avA, avB, zvA, zvB, 0, false, true); ++g;
    // group ngroups-1: steps only
    #pragma unroll
    for (int s = 0; s < GROUP; ++s)
        step(A1[s], B1f[s], avB, s);
    exchange(1, zvB, true);

    // H_final [BS,NH,DS,HD]: H(1023) lives in half1
    if (half) {
        Hf_[hoff]       = H.x;
        Hf_[hoff + 128] = H.y;
        Hf_[hoff + 256] = H.z;
        Hf_[hoff + 384] = H.w;
    }
}
} // namespace

extern "C" void kernel_launch(void* const* d_in, const int* in_sizes, int n_in,
                              void* d_out, int out_size, void* d_ws, size_t ws_size,
                              hipStream_t stream) {
    const float* B_proj     = (const float*)d_in[0];
    const float* X_proj     = (const float*)d_in[1];
    const float* alpha_raw  = (const float*)d_in[2];
    const float* alpha_bias = (const float*)d_in[3];
    const float* z          = (const float*)d_in[4];
    const float* H0         = (const float*)d_in[5];

    float* out = (float*)d_out;                       // [T,BS,DI] then Hf
    float* Hf  = out + (size_t)T * BS * DI;

    const size_t alpha_bytes = (size_t)T * BS * NH * sizeof(float);
    if (ws_size >= alpha_bytes) {
        float* aw = (float*)d_ws;
        alpha_kernel<<<T * BS * NH / 256, 256, 0, stream>>>(alpha_raw, alpha_bias, aw);
        elman_mfma_kernel<true><<<512, 256, 0, stream>>>(
            B_proj, X_proj, aw, alpha_bias, z, H0, out, Hf);
    } else {
        elman_mfma_kernel<false><<<512, 256, 0, stream>>>(
            B_proj, X_proj, alpha_raw, alpha_bias, z, H0, out, Hf);
    }
}

// Round 11
// 319.503 us; speedup vs baseline: 1.7171x; 1.7171x over previous
//
#include <hip/hip_runtime.h>

// StructuredElmanCell via MFMA, split-precision (hi/lo) bf16 inputs.
// Wave owns a 16n x 16p H-tile in fp32 regs; K=32 MFMA carries
// (Bhi*Xhi)+(Bhi*Xlo)+(Blo*Xhi)+(Blo*Xlo) across its 4 k-octets.
// R11: time-split (2 waves/SIMD TLP; half1 starts t=496 from H=0, 48-step
// contraction warmup, emits t>=544 — numerics validated in R10) but built
// with R9's proven register budget: __launch_bounds__(256,1). R10's
// (256,2) made the backend spill the fragment ring (VGPR 136->128, 700 MB
// scratch writes/dispatch, VALUBusy 29%). Warmup groups skip the whole
// exchange (block-uniform condition -> barrier skip is safe).

namespace {
constexpr int T  = 1024;
constexpr int BS = 4;
constexpr int NH = 16;
constexpr int DS = 32;
constexpr int HD = 128;
constexpr int R  = 8;
constexpr int DI = NH * HD;              // 2048
constexpr int GROUP = 8;

// byte strides
constexpr unsigned B_T  = BS * NH * DS * R * 4;  // 65536 B per t
constexpr unsigned X_T  = BS * NH * HD * R * 4;  // 262144 B per t
constexpr unsigned B_G  = B_T * GROUP;
constexpr unsigned X_G  = X_T * GROUP;
constexpr unsigned A_T4 = BS * NH * 4;           // 256 B per t
constexpr unsigned A_G  = A_T4 * GROUP;          // 2048 B per group
constexpr unsigned ZO_T = BS * DI * 4;           // 32768 B per t (z and out)
constexpr unsigned ZO_G = ZO_T * GROUP;          // 262144 B per group

constexpr int SPLIT_T  = 544;   // half0 emits t<544 (68 groups)
constexpr int WARM     = 48;    // half1 warmup steps = 6 groups
constexpr int T_BEGIN1 = SPLIT_T - WARM;         // 496
constexpr int NG0      = SPLIT_T / GROUP;        // 68
constexpr int NG1      = (T - T_BEGIN1) / GROUP; // 66

constexpr float LOG2E = 1.4426950408889634f;

typedef __attribute__((ext_vector_type(8))) short bf16x8;
typedef __attribute__((ext_vector_type(4))) float f32x4;
typedef __attribute__((ext_vector_type(4))) unsigned u32x4;

__device__ __forceinline__ float fast_exp(float x) {
    return __builtin_amdgcn_exp2f(x * LOG2E);
}
__device__ __forceinline__ float fast_silu(float x) {
    return x * __builtin_amdgcn_rcpf(1.0f + __builtin_amdgcn_exp2f(x * -LOG2E));
}
__device__ __forceinline__ float4 ld4(const void* p, unsigned off) {
    return *(const float4*)((const char*)p + off);
}
__device__ __forceinline__ float ld1(const void* p, unsigned off) {
    return *(const float*)((const char*)p + off);
}

// bf16-pair pack: low16 = sel(a), high16 = sel(b); hi = top-16 truncation,
// lo = exact fp32 remainder truncated to bf16.
__device__ __forceinline__ unsigned pack_pair(float a, float b, bool useHi) {
    unsigned ua = __float_as_uint(a), ub = __float_as_uint(b);
    unsigned hi = __builtin_amdgcn_perm(ub, ua, 0x07060302u);
    float la = a - __uint_as_float(ua & 0xffff0000u);   // exact
    float lb = b - __uint_as_float(ub & 0xffff0000u);
    unsigned lo = __builtin_amdgcn_perm(__float_as_uint(lb),
                                        __float_as_uint(la), 0x07060302u);
    return useHi ? hi : lo;
}
__device__ __forceinline__ u32x4 pack_frag(const float4& v0, const float4& v1,
                                           bool useHi) {
    u32x4 u;
    u.x = pack_pair(v0.x, v0.y, useHi);
    u.y = pack_pair(v0.z, v0.w, useHi);
    u.z = pack_pair(v1.x, v1.y, useHi);
    u.w = pack_pair(v1.z, v1.w, useHi);
    return u;
}

// ---------------- pass 0: alpha = 1/(2+exp(ar+ab)) == sigmoid(-softplus) ---
__global__ __launch_bounds__(256)
void alpha_kernel(const float* __restrict__ ar_, const float* __restrict__ ab_,
                  float* __restrict__ alpha_) {
    int i = blockIdx.x * 256 + threadIdx.x;          // [T,BS,NH] flat
    float v = ar_[i] + ab_[i & (NH - 1)];
    alpha_[i] = __builtin_amdgcn_rcpf(2.0f + fast_exp(v));
}

// ---------------- pass 1: MFMA scan, time-split ----------------------------
template<bool PRE>
__global__ __launch_bounds__(256, 1)
void elman_mfma_kernel(const float* __restrict__ B_,
                       const float* __restrict__ X_,
                       const float* __restrict__ a_,   // PRE? alpha : alpha_raw
                       const float* __restrict__ ab_,
                       const float* __restrict__ z_,
                       const float* __restrict__ H0_,
                       float* __restrict__ out_,
                       float* __restrict__ Hf_)
{
    __shared__ float ybuf[2][2][GROUP][9][16];  // [parity][pcl][stage][src+pad][p]

    const int half = blockIdx.x >> 8;           // 0: t<544, 1: t>=496
    const int blk  = blockIdx.x & 255;
    const int lane = threadIdx.x & 63;
    const int W    = blk * 4 + (threadIdx.x >> 6); // tile 0..1023
    const int nc   = W & 1;
    const int pc   = (W >> 1) & 7;
    const int bh   = W >> 4;
    const int h    = bh & (NH - 1);
    const int b    = bh >> 4;
    const int n0   = nc * 16;
    const int p0   = pc * 16;
    const int pcl  = pc & 1;
    const int l15  = lane & 15;
    const int sl   = lane >> 4;          // 0..3
    const int st   = nc * 4 + sl;        // this lane's gate stage AND src id

    const int t_begin   = half ? T_BEGIN1 : 0;
    const int ngroups   = half ? NG1 : NG0;
    const int emit_from = half ? (WARM / GROUP) : 0;

    const bool useBhi = (lane < 32);
    const bool useXhi = ((lane & 16) == 0);

    const unsigned hoff = (unsigned)bh * 4096u
                        + (unsigned)(n0 + sl * 4) * 128u
                        + (unsigned)(p0 + l15);
    f32x4 H;
    if (half) {
        H.x = 0.f; H.y = 0.f; H.z = 0.f; H.w = 0.f;   // warmup: contraction
    } else {
        H.x = H0_[hoff];       H.y = H0_[hoff + 128];
        H.z = H0_[hoff + 256]; H.w = H0_[hoff + 384];
    }

    const float abv = PRE ? 0.0f : ab_[h];

    // byte offsets off SGPR bases, shifted to t_begin
    unsigned bB = ((unsigned)bh * (DS * R) + (unsigned)(n0 + l15) * R) * 4u
                + (unsigned)t_begin * B_T;
    unsigned bX = ((unsigned)bh * (HD * R) + (unsigned)(p0 + l15) * R) * 4u
                + (unsigned)t_begin * X_T;
    unsigned bA = ((unsigned)(lane & 7) * 64u + (unsigned)bh) * 4u
                + (unsigned)t_begin * A_T4;
    const unsigned zo0 = ((unsigned)st * 8192u + (unsigned)b * 2048u
                        + (unsigned)h * 128u + (unsigned)(p0 + l15)) * 4u
                        + (unsigned)t_begin * ZO_T;
    unsigned bZ = zo0, bO = zo0;

    float4 rB0[GROUP], rB1[GROUP], rX0[GROUP], rX1[GROUP];
    u32x4 A0[GROUP], B0f[GROUP], A1[GROUP], B1f[GROUP];
    float py[GROUP];
    float avA, avB, zvA, zvB;

    // ---- prologue: raw g0 -> pack into set0; raw g1 into ring -------------
    #pragma unroll
    for (int s = 0; s < GROUP; ++s) {
        rB0[s] = ld4(B_, bB + (unsigned)s * B_T);
        rB1[s] = ld4(B_, bB + (unsigned)s * B_T + 16u);
        rX0[s] = ld4(X_, bX + (unsigned)s * X_T);
        rX1[s] = ld4(X_, bX + (unsigned)s * X_T + 16u);
    }
    bB += B_G; bX += X_G;
    avA = ld1(a_, bA); bA += A_G;
    zvA = ld1(z_, bZ); bZ += ZO_G;
    #pragma unroll
    for (int s = 0; s < GROUP; ++s) {
        A0[s]  = pack_frag(rB0[s], rB1[s], useBhi);
        B0f[s] = pack_frag(rX0[s], rX1[s], useXhi);
    }
    #pragma unroll
    for (int s = 0; s < GROUP; ++s) {
        rB0[s] = ld4(B_, bB + (unsigned)s * B_T);
        rB1[s] = ld4(B_, bB + (unsigned)s * B_T + 16u);
        rX0[s] = ld4(X_, bX + (unsigned)s * X_T);
        rX1[s] = ld4(X_, bX + (unsigned)s * X_T + 16u);
    }
    bB += B_G; bX += X_G;   // now points at g2

    auto step = [&](const u32x4& af, const u32x4& bf, float avC, int s) {
        float ar = __int_as_float(
            __builtin_amdgcn_readlane(__float_as_int(avC), s));
        float alpha = PRE ? ar
                          : __builtin_amdgcn_rcpf(2.0f + fast_exp(ar + abv));
        f32x4 c;
        c.x = alpha * H.x; c.y = alpha * H.y;
        c.z = alpha * H.z; c.w = alpha * H.w;
        f32x4 d = __builtin_amdgcn_mfma_f32_16x16x32_bf16(
            __builtin_bit_cast(bf16x8, af), __builtin_bit_cast(bf16x8, bf),
            c, 0, 0, 0);
        H.x = fast_silu(d.x); H.y = fast_silu(d.y);
        H.z = fast_silu(d.z); H.w = fast_silu(d.w);
        py[s] = (H.x + H.y) + (H.z + H.w);
    };

    auto exchange = [&](int par, float zvC) {
        #pragma unroll
        for (int s = 0; s < GROUP; ++s)
            ybuf[par][pcl][s][st][l15] = py[s];
        asm volatile("s_waitcnt lgkmcnt(0)" ::: "memory");
        __builtin_amdgcn_s_barrier();
        __builtin_amdgcn_sched_barrier(0);
        asm volatile("" ::: "memory");
        float y2 = 0.0f;
        #pragma unroll
        for (int k = 0; k < 8; ++k)
            y2 += ybuf[par][pcl][st][k][l15];
        float g = y2 * fast_silu(zvC + y2);
        *(float*)((char*)out_ + bO) = g;
    };

    // body for one group: steps from (Ac,Bc); pack ring -> (An,Bn); refill ring
    auto body = [&](u32x4 (&Ac)[GROUP], u32x4 (&Bc)[GROUP],
                    u32x4 (&An)[GROUP], u32x4 (&Bn)[GROUP],
                    float avC, float& avN, float zvC, float& zvN,
                    int par, bool refill, bool emit) {
        avN = ld1(a_, bA); bA += A_G;
        zvN = ld1(z_, bZ); bZ += ZO_G;
        #pragma unroll
        for (int s = 0; s < GROUP; ++s) {
            step(Ac[s], Bc[s], avC, s);
            An[s] = pack_frag(rB0[s], rB1[s], useBhi);
            Bn[s] = pack_frag(rX0[s], rX1[s], useXhi);
            if (refill) {
                rB0[s] = ld4(B_, bB + (unsigned)s * B_T);
                rB1[s] = ld4(B_, bB + (unsigned)s * B_T + 16u);
                rX0[s] = ld4(X_, bX + (unsigned)s * X_T);
                rX1[s] = ld4(X_, bX + (unsigned)s * X_T + 16u);
            }
        }
        if (refill) { bB += B_G; bX += X_G; }
        if (emit) exchange(par, zvC);     // block-uniform: barrier skip safe
        bO += ZO_G;
    };

    // main: ping-pong pairs; refill g+2 valid through g = ngroups-3
    int g = 0;
    #pragma unroll 1
    for (int gg = 0; gg < (ngroups - 2) / 2; ++gg) {
        body(A0, B0f, A1, B1f, avA, avB, zvA, zvB, 0, true, g >= emit_from); ++g;
        body(A1, B1f, A0, B0f, avB, avA, zvB, zvA, 1, true, g >= emit_from); ++g;
    }
    // group ngroups-2: pack last group from ring, no refill
    body(A0, B0f, A1, B1f, avA, avB, zvA, zvB, 0, false, true); ++g;
    // group ngroups-1: steps only
    #pragma unroll
    for (int s = 0; s < GROUP; ++s)
        step(A1[s], B1f[s], avB, s);
    exchange(1, zvB);

    // H_final [BS,NH,DS,HD]: H(1023) lives in half1
    if (half) {
        Hf_[hoff]       = H.x;
        Hf_[hoff + 128] = H.y;
        Hf_[hoff + 256] = H.z;
        Hf_[hoff + 384] = H.w;
    }
}
} // namespace

extern "C" void kernel_launch(void* const* d_in, const int* in_sizes, int n_in,
                              void* d_out, int out_size, void* d_ws, size_t ws_size,
                              hipStream_t stream) {
    const float* B_proj     = (const float*)d_in[0];
    const float* X_proj     = (const float*)d_in[1];
    const float* alpha_raw  = (const float*)d_in[2];
    const float* alpha_bias = (const float*)d_in[3];
    const float* z          = (const float*)d_in[4];
    const float* H0         = (const float*)d_in[5];

    float* out = (float*)d_out;                       // [T,BS,DI] then Hf
    float* Hf  = out + (size_t)T * BS * DI;

    const size_t alpha_bytes = (size_t)T * BS * NH * sizeof(float);
    if (ws_size >= alpha_bytes) {
        float* aw = (float*)d_ws;
        alpha_kernel<<<T * BS * NH / 256, 256, 0, stream>>>(alpha_raw, alpha_bias, aw);
        elman_mfma_kernel<true><<<512, 256, 0, stream>>>(
            B_proj, X_proj, aw, alpha_bias, z, H0, out, Hf);
    } else {
        elman_mfma_kernel<false><<<512, 256, 0, stream>>>(
            B_proj, X_proj, alpha_raw, alpha_bias, z, H0, out, Hf);
    }
}